// Round 2
// 904.640 us; speedup vs baseline: 1.0850x; 1.0850x over previous
//
#include <hip/hip_runtime.h>

#define HH 352
#define WWID 352
#define HW 123904
#define NIMG 2
#define C128 128
#define SCALE_F 0.08838834764831845f

typedef _Float16 f16x8 __attribute__((ext_vector_type(8)));
typedef float f32x4 __attribute__((ext_vector_type(4)));

__device__ __forceinline__ float silu_f(float v){ return v / (1.0f + __expf(-v)); }

// ============ weight pre-swizzle into A-fragment order for mfma_f32_16x16x32_f16.
__global__ __launch_bounds__(256) void k_wprep(const float* __restrict__ W,
                                               _Float16* __restrict__ Wf, int nct){
  int e = blockIdx.x*256 + threadIdx.x;
  if (e >= nct*256) return;
  int l = e & 63, kc = (e>>6)&3, ct = e>>8;
  const float* src = W + (size_t)(ct*16 + (l&15))*128 + kc*32 + (l>>4)*8;
  f16x8 pk;
#pragma unroll
  for (int j=0;j<8;j++) pk[j] = (_Float16)src[j];
  *(f16x8*)(Wf + (size_t)e*8) = pk;
}

// ============ 1x1 conv + silu via fp16 MFMA. Block covers a 4-row x 16-col tile.
// nt-group = one image row of 16 px (same store coalescing as before).
//  FUSEW: full-tile sum per co -> 1 atomicAdd per tile (16/window vs 64 before)
//  FUSEP: the 4x16 tile covers the top or bottom half of two 8x8 pooling cells;
//         half-cell max computed in-register + shfl -> PLAIN store into kvd2
//         (2 slots per cell, folded by k_attention). No atomicMax anywhere.
template<int COW, bool SAMP, bool FUSEW, bool FUSEP>
__global__ __launch_bounds__(256) void k_conv_mfma(const float* __restrict__ X,
                                                   const float* __restrict__ samp,
                                                   const _Float16* __restrict__ Wf,
                                                   const float* __restrict__ B,
                                                   float* __restrict__ O,
                                                   float* __restrict__ winsum,
                                                   float* __restrict__ kvd2){
  constexpr int Cout = COW*4;
  constexpr int MT = COW/16;
  __shared__ _Float16 Xs[16*64*8];
  __shared__ int ibs[64];
  __shared__ float4 wls[64];
  const int t = threadIdx.x;
  const int bx = blockIdx.x;
  const int ty4 = (bx/22)*4, tx16 = (bx - (bx/22)*22)*16;   // 88 x 22 tiles
  const int n = blockIdx.z;
  const int wv = t>>6, l = t&63;
  const float* Xn = X + (size_t)n*C128*HW;
  if (SAMP){
    if (t < 64){
      int fr = ty4 + (t>>4), fc = tx16 + (t&15);
      size_t si = ((size_t)n*HW + (size_t)fr*WWID + fc)*2;
      float gx = samp[si + 0];
      float gy = samp[si + 1];
      float x0f = floorf(gx), y0f = floorf(gy);
      int x0 = (int)x0f, y0 = (int)y0f;  // CLAMP=0.12 -> interior guaranteed
      float fx = gx - x0f, fy = gy - y0f;
      ibs[t] = y0*WWID + x0;
      wls[t] = make_float4((1.f-fx)*(1.f-fy), fx*(1.f-fy), (1.f-fx)*fy, fx*fy);
    }
    __syncthreads();
  }
  const int flatL = (ty4 + (l>>4))*WWID + tx16 + (l&15);
  int ib = 0; float4 wl = make_float4(0.f,0.f,0.f,0.f);
  if (SAMP){ ib = ibs[l]; wl = wls[l]; }
#pragma unroll
  for (int it=0; it<4; it++){
    int kb = it*4 + wv;
    f16x8 pk;
#pragma unroll
    for (int j=0;j<8;j++){
      int ci = kb*8 + j;
      float v;
      if (SAMP){
        const float* Xc = Xn + (size_t)ci*HW + ib;
        v = wl.x*Xc[0] + wl.y*Xc[1] + wl.z*Xc[WWID] + wl.w*Xc[WWID+1];
      } else {
        v = Xn[(size_t)ci*HW + flatL];
      }
      pk[j] = (_Float16)v;
    }
    *(f16x8*)(&Xs[(kb*64 + l)*8]) = pk;
  }
  __syncthreads();
  const int quad = l>>4, li = l&15;
  f32x4 acc[MT][4];
#pragma unroll
  for (int m=0;m<MT;m++)
#pragma unroll
    for (int nt=0;nt<4;nt++){ acc[m][nt][0]=0.f; acc[m][nt][1]=0.f; acc[m][nt][2]=0.f; acc[m][nt][3]=0.f; }
  const _Float16* Wfw = Wf + (size_t)(wv*MT)*4*64*8;
#pragma unroll
  for (int kc=0; kc<4; kc++){
    f16x8 b[4];
#pragma unroll
    for (int nt=0; nt<4; nt++)
      b[nt] = *(const f16x8*)(&Xs[((kc*4 + quad)*64 + nt*16 + li)*8]);
    f16x8 a[MT];
#pragma unroll
    for (int m=0;m<MT;m++)
      a[m] = *(const f16x8*)(Wfw + (size_t)((m*4 + kc)*64 + l)*8);
#pragma unroll
    for (int m=0;m<MT;m++)
#pragma unroll
      for (int nt=0;nt<4;nt++)
        acc[m][nt] = __builtin_amdgcn_mfma_f32_16x16x32_f16(a[m], b[nt], acc[m][nt], 0, 0, 0);
  }
  // epilogue: bias+silu, store, fused window reductions (atomicMax-free).
  const int p = (ty4>>5)*11 + (tx16>>5);
#pragma unroll
  for (int m=0;m<MT;m++){
    int cob = wv*COW + m*16 + quad*4;
#pragma unroll
    for (int r=0;r<4;r++){
      int co = cob + r;
      float bb = B[co];
      float* Op = O + ((size_t)n*Cout + co)*HW + (size_t)ty4*WWID + tx16 + li;
      float ys[4];
#pragma unroll
      for (int nt=0;nt<4;nt++){
        float y = silu_f(acc[m][nt][r] + bb);
        ys[nt] = y;
        Op[nt*WWID] = y;
      }
      if (FUSEW && co < 128){
        float ssum = ys[0] + ys[1] + ys[2] + ys[3];
        ssum += __shfl_xor(ssum,1); ssum += __shfl_xor(ssum,2);
        ssum += __shfl_xor(ssum,4); ssum += __shfl_xor(ssum,8);
        if (li == 0)
          atomicAdd(winsum + ((size_t)n*121 + p)*128 + co, ssum);
      }
      if (FUSEP){
        float mx = fmaxf(fmaxf(ys[0],ys[1]), fmaxf(ys[2],ys[3]));
        mx = fmaxf(mx, __shfl_xor(mx,1));
        mx = fmaxf(mx, __shfl_xor(mx,2));
        mx = fmaxf(mx, __shfl_xor(mx,4));
        if ((li & 7) == 0){
          int cell = ((ty4>>3)&3)*4 + ((tx16>>3)&3) + (li>>3);
          int vh = (ty4>>2)&1;
          kvd2[((((size_t)n*121 + p)*16 + cell)*2 + vh)*256 + co] = mx;
        }
      }
    }
  }
}

// ============ offset path, channel-split: each block does 32 channels of dw9x9+BN+pw over a
// 32x16 tile, partial-reduced into offacc via atomicAdd. grid (11, 22, N*4), block 256.
__global__ __launch_bounds__(256) void k_offset_part(const float* __restrict__ q,
                                                     const float* __restrict__ dww,
                                                     const float* __restrict__ dwb,
                                                     const float* __restrict__ bng,
                                                     const float* __restrict__ bnb,
                                                     const float* __restrict__ pw,
                                                     float* __restrict__ offacc){
  __shared__ float s[3840];   // [4ch][960], 960 = 24 rows x 40 cols halo tile
  const int t = threadIdx.x;
  const int X0 = blockIdx.x*32, Y0 = blockIdx.y*16;
  const int n = blockIdx.z >> 2, c0 = (blockIdx.z & 3)*32;
  const int tx = t & 15, ty = t >> 4;
  const int px = X0 + tx*2, py = Y0 + ty;
  const float inv = 1.0f / sqrtf(1.0f + 1e-5f);
  float o0a=0.f,o0b=0.f,o1a=0.f,o1b=0.f;
  float pf[15];
  const float* qn = q + (size_t)n*C128*HW;
  auto issue = [&](int stage){
    int cbase = c0 + stage*4;
#pragma unroll
    for (int i=0;i<15;i++){
      int e = t + i*256;
      int ch = e/960, idx = e - ch*960;
      int rr = idx/40, cc2 = idx - rr*40;
      int gr = Y0 - 4 + rr, gc = X0 - 4 + cc2;
      float v = 0.f;
      if (gr>=0 && gr<HH && gc>=0 && gc<WWID) v = qn[(size_t)(cbase+ch)*HW + gr*WWID + gc];
      pf[i] = v;
    }
  };
  issue(0);
  for (int stage=0; stage<8; stage++){
    __syncthreads();
#pragma unroll
    for (int i=0;i<15;i++) s[t + i*256] = pf[i];
    __syncthreads();
    if (stage < 7) issue(stage+1);
    int cbase = c0 + stage*4;
#pragma unroll
    for (int ch=0; ch<4; ch++){
      int c = cbase + ch;
      const float* wc = dww + c*81;
      const float* sc = s + ch*960;
      float sum0=0.f, sum1=0.f;
#pragma unroll
      for (int r=0;r<9;r++){
        float ld[10];
#pragma unroll
        for (int m2=0;m2<5;m2++){
          float2 v2 = *(const float2*)(sc + (ty+r)*40 + tx*2 + 2*m2);
          ld[2*m2]=v2.x; ld[2*m2+1]=v2.y;
        }
#pragma unroll
        for (int j=0;j<9;j++){
          float wv = wc[r*9+j];
          sum0 += wv*ld[j]; sum1 += wv*ld[j+1];
        }
      }
      float g = inv*bng[c], bet = bnb[c], db = dwb[c];
      float t0 = (sum0+db)*g + bet, t1 = (sum1+db)*g + bet;
      float p0c = pw[c], p1c = pw[C128+c];
      o0a += p0c*t0; o0b += p0c*t1;
      o1a += p1c*t0; o1b += p1c*t1;
    }
  }
  size_t base = ((size_t)n*HW + (size_t)py*WWID + px)*2;
  atomicAdd(offacc + base + 0, o0a);
  atomicAdd(offacc + base + 1, o1a);
  atomicAdd(offacc + base + 2, o0b);
  atomicAdd(offacc + base + 3, o1b);
}

// ============ finalize: offacc -> clamp -> pixel coords. grid (N*HW/256).
__global__ __launch_bounds__(256) void k_samp_fin(const float* __restrict__ offacc,
                                                  float* __restrict__ samp){
  int e = blockIdx.x*256 + threadIdx.x;
  int n = e / HW, p = e - n*HW;
  int py = p / WWID, px = p - py*WWID;
  float2 o2 = *(const float2*)(offacc + (size_t)e*2);
  const float k2 = 2.0f/351.0f;
  float ry = (0.5f+(float)py)*k2 - 1.0f, rx = (0.5f+(float)px)*k2 - 1.0f;
  float pyc = fminf(fmaxf(o2.x+ry,-0.12f),0.12f);
  float pxc = fminf(fmaxf(o2.y+rx,-0.12f),0.12f);
  float2 o; o.x = (pxc+1.f)*0.5f*351.f; o.y = (pyc+1.f)*0.5f*351.f;
  *(float2*)(samp + (size_t)e*2) = o;
  (void)n;
}

// ============ routing: logits row + top-4 indices (order-only; winsums are unscaled means).
__global__ __launch_bounds__(64) void k_routing(const float* __restrict__ qwin,
                                               const float* __restrict__ kwin,
                                               int* __restrict__ topidx){
  __shared__ float lg[128];
  const int p = blockIdx.x, n = blockIdx.y, l = threadIdx.x;
  const float* qr = qwin + ((size_t)n*121 + p)*128;
  const float* kb = kwin + (size_t)n*121*128;
  float a0 = 0.f, a1 = 0.f;
  const bool has1 = (l + 64) < 121;
  for (int c=0;c<128;c++){
    float qv = qr[c];
    a0 += qv * kb[(size_t)l*128 + c];
    if (has1) a1 += qv * kb[(size_t)(l+64)*128 + c];
  }
  lg[l] = a0;
  lg[64+l] = has1 ? a1 : -3.0e38f;
  __syncthreads();
  if (l == 0){
    for (int j=0;j<4;j++){
      float best = -3.0e38f; int bi = 0;
      for (int i=0;i<121;i++){ if (lg[i] > best){ best = lg[i]; bi = i; } }
      lg[bi] = -3.0e38f;
      topidx[((size_t)n*121 + p)*4 + j] = bi;
    }
  }
}

// ============ windowed attention. grid (121, N, 4 heads), block 256. 2 px/lane.
// kvd2 has two half-cell maxes per cell -> fold with fmaxf while staging to LDS.
__global__ __launch_bounds__(256) void k_attention(const float* __restrict__ q,
                                                   const float* __restrict__ kvd2,
                                                   const int* __restrict__ topidx,
                                                   float* __restrict__ out){
  __shared__ float ks[64*32];
  __shared__ float vs[64*32];
  __shared__ int tix[4];
  const int p = blockIdx.x, n = blockIdx.y, h = blockIdx.z;
  const int t = threadIdx.x;
  if (t < 4) tix[t] = topidx[((size_t)n*121 + p)*4 + t];
  __syncthreads();
#pragma unroll
  for (int i=0;i<8;i++){
    int e = t + i*256;
    int d = e & 31, k = e >> 5;
    const float* kr = kvd2 + ((((size_t)(n*121) + tix[k>>4])*16 + (k & 15))*2)*256;
    ks[k*32 + d] = fmaxf(kr[h*32 + d],       kr[256 + h*32 + d]);
    vs[k*32 + d] = fmaxf(kr[128 + h*32 + d], kr[384 + h*32 + d]);
  }
  __syncthreads();
  const int py0 = (p/11)*32, px0 = (p%11)*32;
  const int wv = t >> 6, l = t & 63;
  const float* qh = q + ((size_t)n*C128 + h*32)*HW;
  float* oh = out + ((size_t)n*C128 + h*32)*HW;
  for (int it=0; it<2; it++){
    int pxa = it*512 + wv*128 + l;
    int pxb = pxa + 64;
    size_t offa = (size_t)(py0 + (pxa>>5))*WWID + px0 + (pxa&31);
    size_t offb = (size_t)(py0 + (pxb>>5))*WWID + px0 + (pxb&31);
    float qa[32], qb[32], oa[32], ob[32];
#pragma unroll
    for (int d=0; d<32; d++){
      qa[d] = qh[(size_t)d*HW + offa] * SCALE_F;
      qb[d] = qh[(size_t)d*HW + offb] * SCALE_F;
      oa[d] = 0.f; ob[d] = 0.f;
    }
    float suma = 0.f, sumb = 0.f;
    for (int k=0; k<64; k++){
      const float4* kk4 = (const float4*)(ks + k*32);
      float da = 0.f, db = 0.f;
#pragma unroll
      for (int d4=0; d4<8; d4++){
        float4 kk = kk4[d4];
        da += qa[d4*4+0]*kk.x + qa[d4*4+1]*kk.y + qa[d4*4+2]*kk.z + qa[d4*4+3]*kk.w;
        db += qb[d4*4+0]*kk.x + qb[d4*4+1]*kk.y + qb[d4*4+2]*kk.z + qb[d4*4+3]*kk.w;
      }
      float pa = __expf(da), pb = __expf(db);
      suma += pa; sumb += pb;
      const float4* vv4 = (const float4*)(vs + k*32);
#pragma unroll
      for (int d4=0; d4<8; d4++){
        float4 vvv = vv4[d4];
        oa[d4*4+0] += pa*vvv.x; oa[d4*4+1] += pa*vvv.y; oa[d4*4+2] += pa*vvv.z; oa[d4*4+3] += pa*vvv.w;
        ob[d4*4+0] += pb*vvv.x; ob[d4*4+1] += pb*vvv.y; ob[d4*4+2] += pb*vvv.z; ob[d4*4+3] += pb*vvv.w;
      }
    }
    float ia = 1.0f/suma, ib2 = 1.0f/sumb;
#pragma unroll
    for (int d=0; d<32; d++){
      oh[(size_t)d*HW + offa] = oa[d]*ia;
      oh[(size_t)d*HW + offb] = ob[d]*ib2;
    }
  }
}

// ============ sec: depthwise 3x3 over V-half of kv, added into out. grid (121 tiles, C, N).
__global__ __launch_bounds__(256) void k_sec_add(const float* __restrict__ kv,
                                                 const float* __restrict__ secw,
                                                 const float* __restrict__ secb,
                                                 float* __restrict__ out){
  __shared__ float s[34*34];
  const int t = threadIdx.x;
  const int bx = blockIdx.x, c = blockIdx.y, n = blockIdx.z;
  const int X0 = (bx % 11)*32, Y0 = (bx / 11)*32;
  const float* src = kv + ((size_t)n*256 + 128 + c)*HW;
  for (int e = t; e < 1156; e += 256){
    int row = e / 34;
    int col = e - row*34;
    int gr = Y0 - 1 + row, gc = X0 - 1 + col;
    s[e] = (gr >= 0 && gr < HH && gc >= 0 && gc < WWID) ? src[gr*WWID + gc] : 0.f;
  }
  __syncthreads();
  const int tx = (t & 7)*4, ty = t >> 3;
  float w[9];
#pragma unroll
  for (int i=0;i<9;i++) w[i] = secw[c*9 + i];
  float4 r = make_float4(0.f,0.f,0.f,0.f);
#pragma unroll
  for (int kr=0; kr<3; kr++){
    const float* row = s + (ty + kr)*34 + tx;
    float a0=row[0],a1=row[1],a2=row[2],a3=row[3],a4=row[4],a5=row[5];
    float w0=w[kr*3], w1=w[kr*3+1], w2=w[kr*3+2];
    r.x += w0*a0 + w1*a1 + w2*a2;
    r.y += w0*a1 + w1*a2 + w2*a3;
    r.z += w0*a2 + w1*a3 + w2*a4;
    r.w += w0*a3 + w1*a4 + w2*a5;
  }
  float bb = secb[c];
  float* op = out + ((size_t)n*C128 + c)*HW + (size_t)(Y0+ty)*WWID + X0 + tx;
  float4 cur = *(float4*)op;
  cur.x += r.x + bb; cur.y += r.y + bb; cur.z += r.z + bb; cur.w += r.w + bb;
  *(float4*)op = cur;
}

extern "C" void kernel_launch(void* const* d_in, const int* in_sizes, int n_in,
                              void* d_out, int out_size, void* d_ws, size_t ws_size,
                              hipStream_t stream) {
  const float* x        = (const float*)d_in[0];
  const float* q_w      = (const float*)d_in[1];
  const float* q_b      = (const float*)d_in[2];
  const float* kv_w     = (const float*)d_in[3];
  const float* kv_b     = (const float*)d_in[4];
  const float* off_dw_w = (const float*)d_in[5];
  const float* off_dw_b = (const float*)d_in[6];
  const float* off_bn_g = (const float*)d_in[7];
  const float* off_bn_b = (const float*)d_in[8];
  const float* off_pw_w = (const float*)d_in[9];
  const float* sec_w    = (const float*)d_in[10];
  const float* sec_b    = (const float*)d_in[11];
  float* outp = (float*)d_out;

  float* qbuf  = (float*)d_ws;                               // N*128*HW
  float* kvbuf = qbuf  + (size_t)NIMG*C128*HW;               // N*256*HW
  float* samp  = kvbuf + (size_t)NIMG*256*HW;                // N*HW*2
  float* qwin  = samp  + (size_t)NIMG*HW*2;                  // N*121*128 (zeroed)
  float* kwin  = qwin  + (size_t)NIMG*121*128;               // N*121*128 (zeroed)
  float* kvd2  = kwin  + (size_t)NIMG*121*128;               // N*121*16*2*256 (all slots stored)
  int*   tidx  = (int*)(kvd2 + (size_t)NIMG*121*16*2*256);   // N*121*4
  _Float16* wfq  = (_Float16*)(tidx + NIMG*121*4);           // 16384 f16
  _Float16* wfkv = wfq + 16384;                              // 32768 f16
  // offacc aliases the head of kvbuf: dead (consumed by k_samp_fin) before conv64 writes kvbuf.
  float* offacc = kvbuf;                                     // N*HW*2 (zeroed)

  hipMemsetAsync(offacc, 0, (size_t)NIMG*HW*2*4, stream);
  hipMemsetAsync(qwin, 0, (size_t)NIMG*121*128*2*4, stream);

  k_wprep<<<dim3(8), 256, 0, stream>>>(q_w, wfq, 8);
  k_wprep<<<dim3(16), 256, 0, stream>>>(kv_w, wfkv, 16);
  k_conv_mfma<32, false, true, false><<<dim3(88*22, 1, NIMG), 256, 0, stream>>>(
      x, nullptr, wfq, q_b, qbuf, qwin, nullptr);
  k_offset_part<<<dim3(11, 22, NIMG*4), 256, 0, stream>>>(
      qbuf, off_dw_w, off_dw_b, off_bn_g, off_bn_b, off_pw_w, offacc);
  k_samp_fin<<<dim3(NIMG*HW/256), 256, 0, stream>>>(offacc, samp);
  k_conv_mfma<64, true, true, true><<<dim3(88*22, 1, NIMG), 256, 0, stream>>>(
      x, samp, wfkv, kv_b, kvbuf, kwin, kvd2);
  k_routing<<<dim3(121, NIMG), 64, 0, stream>>>(qwin, kwin, tidx);
  k_attention<<<dim3(121, NIMG, 4), 256, 0, stream>>>(qbuf, kvd2, tidx, outp);
  k_sec_add<<<dim3(121, 128, NIMG), 256, 0, stream>>>(kvbuf, sec_w, sec_b, outp);
}

// Round 3
// 823.489 us; speedup vs baseline: 1.1919x; 1.0985x over previous
//
#include <hip/hip_runtime.h>

#define HH 352
#define WWID 352
#define HW 123904
#define NIMG 2
#define C128 128
#define SCALE_F 0.08838834764831845f

typedef _Float16 f16x8 __attribute__((ext_vector_type(8)));
typedef float f32x4 __attribute__((ext_vector_type(4)));

__device__ __forceinline__ float silu_f(float v){ return v / (1.0f + __expf(-v)); }

// ============ weight pre-swizzle into A-fragment order for mfma_f32_16x16x32_f16.
__global__ __launch_bounds__(256) void k_wprep(const float* __restrict__ W,
                                               _Float16* __restrict__ Wf, int nct){
  int e = blockIdx.x*256 + threadIdx.x;
  if (e >= nct*256) return;
  int l = e & 63, kc = (e>>6)&3, ct = e>>8;
  const float* src = W + (size_t)(ct*16 + (l&15))*128 + kc*32 + (l>>4)*8;
  f16x8 pk;
#pragma unroll
  for (int j=0;j<8;j++) pk[j] = (_Float16)src[j];
  *(f16x8*)(Wf + (size_t)e*8) = pk;
}

// ============ 1x1 conv + silu via fp16 MFMA. Block covers a 4-row x 16-col tile.
//  FUSEW: full-tile sum per co -> 1 atomicAdd per tile
//  FUSEP: half-cell (4x8) max -> plain store into kvd2 (folded by k_attention)
template<int COW, bool SAMP, bool FUSEW, bool FUSEP>
__global__ __launch_bounds__(256) void k_conv_mfma(const float* __restrict__ X,
                                                   const float* __restrict__ samp,
                                                   const _Float16* __restrict__ Wf,
                                                   const float* __restrict__ B,
                                                   float* __restrict__ O,
                                                   float* __restrict__ winsum,
                                                   float* __restrict__ kvd2){
  constexpr int Cout = COW*4;
  constexpr int MT = COW/16;
  __shared__ _Float16 Xs[16*64*8];
  __shared__ int ibs[64];
  __shared__ float4 wls[64];
  const int t = threadIdx.x;
  const int bx = blockIdx.x;
  const int ty4 = (bx/22)*4, tx16 = (bx - (bx/22)*22)*16;   // 88 x 22 tiles
  const int n = blockIdx.z;
  const int wv = t>>6, l = t&63;
  const float* Xn = X + (size_t)n*C128*HW;
  if (SAMP){
    if (t < 64){
      int fr = ty4 + (t>>4), fc = tx16 + (t&15);
      size_t si = ((size_t)n*HW + (size_t)fr*WWID + fc)*2;
      float gx = samp[si + 0];
      float gy = samp[si + 1];
      float x0f = floorf(gx), y0f = floorf(gy);
      int x0 = (int)x0f, y0 = (int)y0f;  // CLAMP=0.12 -> interior guaranteed
      float fx = gx - x0f, fy = gy - y0f;
      ibs[t] = y0*WWID + x0;
      wls[t] = make_float4((1.f-fx)*(1.f-fy), fx*(1.f-fy), (1.f-fx)*fy, fx*fy);
    }
    __syncthreads();
  }
  const int flatL = (ty4 + (l>>4))*WWID + tx16 + (l&15);
  int ib = 0; float4 wl = make_float4(0.f,0.f,0.f,0.f);
  if (SAMP){ ib = ibs[l]; wl = wls[l]; }
#pragma unroll
  for (int it=0; it<4; it++){
    int kb = it*4 + wv;
    f16x8 pk;
#pragma unroll
    for (int j=0;j<8;j++){
      int ci = kb*8 + j;
      float v;
      if (SAMP){
        const float* Xc = Xn + (size_t)ci*HW + ib;
        v = wl.x*Xc[0] + wl.y*Xc[1] + wl.z*Xc[WWID] + wl.w*Xc[WWID+1];
      } else {
        v = Xn[(size_t)ci*HW + flatL];
      }
      pk[j] = (_Float16)v;
    }
    *(f16x8*)(&Xs[(kb*64 + l)*8]) = pk;
  }
  __syncthreads();
  const int quad = l>>4, li = l&15;
  f32x4 acc[MT][4];
#pragma unroll
  for (int m=0;m<MT;m++)
#pragma unroll
    for (int nt=0;nt<4;nt++){ acc[m][nt][0]=0.f; acc[m][nt][1]=0.f; acc[m][nt][2]=0.f; acc[m][nt][3]=0.f; }
  const _Float16* Wfw = Wf + (size_t)(wv*MT)*4*64*8;
#pragma unroll
  for (int kc=0; kc<4; kc++){
    f16x8 b[4];
#pragma unroll
    for (int nt=0; nt<4; nt++)
      b[nt] = *(const f16x8*)(&Xs[((kc*4 + quad)*64 + nt*16 + li)*8]);
    f16x8 a[MT];
#pragma unroll
    for (int m=0;m<MT;m++)
      a[m] = *(const f16x8*)(Wfw + (size_t)((m*4 + kc)*64 + l)*8);
#pragma unroll
    for (int m=0;m<MT;m++)
#pragma unroll
      for (int nt=0;nt<4;nt++)
        acc[m][nt] = __builtin_amdgcn_mfma_f32_16x16x32_f16(a[m], b[nt], acc[m][nt], 0, 0, 0);
  }
  // epilogue: bias+silu, store, fused window reductions (atomicMax-free).
  const int p = (ty4>>5)*11 + (tx16>>5);
#pragma unroll
  for (int m=0;m<MT;m++){
    int cob = wv*COW + m*16 + quad*4;
#pragma unroll
    for (int r=0;r<4;r++){
      int co = cob + r;
      float bb = B[co];
      float* Op = O + ((size_t)n*Cout + co)*HW + (size_t)ty4*WWID + tx16 + li;
      float ys[4];
#pragma unroll
      for (int nt=0;nt<4;nt++){
        float y = silu_f(acc[m][nt][r] + bb);
        ys[nt] = y;
        Op[nt*WWID] = y;
      }
      if (FUSEW && co < 128){
        float ssum = ys[0] + ys[1] + ys[2] + ys[3];
        ssum += __shfl_xor(ssum,1); ssum += __shfl_xor(ssum,2);
        ssum += __shfl_xor(ssum,4); ssum += __shfl_xor(ssum,8);
        if (li == 0)
          atomicAdd(winsum + ((size_t)n*121 + p)*128 + co, ssum);
      }
      if (FUSEP){
        float mx = fmaxf(fmaxf(ys[0],ys[1]), fmaxf(ys[2],ys[3]));
        mx = fmaxf(mx, __shfl_xor(mx,1));
        mx = fmaxf(mx, __shfl_xor(mx,2));
        mx = fmaxf(mx, __shfl_xor(mx,4));
        if ((li & 7) == 0){
          int cell = ((ty4>>3)&3)*4 + ((tx16>>3)&3) + (li>>3);
          int vh = (ty4>>2)&1;
          kvd2[((((size_t)n*121 + p)*16 + cell)*2 + vh)*256 + co] = mx;
        }
      }
    }
  }
}

// ============ offset path v2: 8 px/thread sliding window, wave-uniform channel,
// atomic-free partial output. grid (11,22,N*4) with XCD-chunked swizzle, block 256.
// Per stage: 4 channels (one per wave), LDS [4][24 rows x 44-stride (40 used)].
__global__ __launch_bounds__(256) void k_offset_part(const float* __restrict__ q,
                                                     const float* __restrict__ dww,
                                                     const float* __restrict__ dwb,
                                                     const float* __restrict__ bng,
                                                     const float* __restrict__ bnb,
                                                     const float* __restrict__ pw,
                                                     float* __restrict__ offpart){
  __shared__ float s[4224];   // 4 ch x 1056 (24 x 44)
  const int t = threadIdx.x;
  // XCD-chunked swizzle: 1936 blocks, 242 consecutive logical tiles per XCD.
  int id = blockIdx.x + 11*(blockIdx.y + 22*blockIdx.z);
  int lid = (id & 7)*242 + (id >> 3);
  int bx = lid % 11; int rest = lid / 11;
  int by = rest % 22; int zz = rest / 22;
  const int X0 = bx*32, Y0 = by*16;
  const int n = zz >> 2, cg = zz & 3, c0 = cg*32;
  const int w = __builtin_amdgcn_readfirstlane(t >> 6);   // wave id = channel lane
  const int l = t & 63;
  const int cg2 = l & 3, rowi = l >> 2;                   // 4 col-groups x 16 rows
  const float inv = 1.0f / sqrtf(1.0f + 1e-5f);
  const float* qn = q + (size_t)n*C128*HW;
  float o0[8], o1[8];
#pragma unroll
  for (int j=0;j<8;j++){ o0[j]=0.f; o1[j]=0.f; }
  float K0 = 0.f, K1 = 0.f;
  float pf[17];
  auto issue = [&](int stage){
    int cbase = c0 + stage*4;
#pragma unroll
    for (int i=0;i<17;i++){
      if (i == 16 && t >= 128) continue;   // e < 4224
      int e = t + i*256;
      int ch = e/1056, idx = e - ch*1056;
      int rr = idx/44, cc = idx - rr*44;
      int gr = Y0 - 4 + rr, gc = X0 - 4 + cc;
      float v = 0.f;
      if (cc < 40 && gr>=0 && gr<HH && gc>=0 && gc<WWID)
        v = qn[(size_t)(cbase+ch)*HW + gr*WWID + gc];
      pf[i] = v;
    }
  };
  issue(0);
  for (int stage=0; stage<8; stage++){
    __syncthreads();
#pragma unroll
    for (int i=0;i<17;i++){
      if (i == 16 && t >= 128) continue;
      s[t + i*256] = pf[i];
    }
    __syncthreads();
    if (stage < 7) issue(stage+1);
    const int c = c0 + stage*4 + w;
    const float* wc = dww + c*81;            // wave-uniform -> s_load weights
    const float* scp = s + w*1056 + rowi*44 + cg2*8;
    float sum[8];
#pragma unroll
    for (int j=0;j<8;j++) sum[j]=0.f;
#pragma unroll
    for (int r=0;r<9;r++){
      float f[16];
      const float4* s4 = (const float4*)(scp + r*44);
#pragma unroll
      for (int m2=0;m2<4;m2++){
        float4 v4 = s4[m2];
        f[4*m2]=v4.x; f[4*m2+1]=v4.y; f[4*m2+2]=v4.z; f[4*m2+3]=v4.w;
      }
#pragma unroll
      for (int k=0;k<9;k++){
        float wv = wc[r*9+k];
#pragma unroll
        for (int j=0;j<8;j++) sum[j] += wv * f[j+k];
      }
    }
    float g = inv*bng[c], bet = bnb[c], db = dwb[c];
    float p0c = pw[c], p1c = pw[C128+c];
    float A0 = p0c*g, A1 = p1c*g;
    float Cc = g*db + bet;
    K0 += p0c*Cc; K1 += p1c*Cc;
#pragma unroll
    for (int j=0;j<8;j++){ o0[j] += A0*sum[j]; o1[j] += A1*sum[j]; }
  }
  // cross-wave reduce via LDS (reuse s): [w][l][16] at s[0..4095], K at s[4096+w*2+o]
  __syncthreads();
#pragma unroll
  for (int j=0;j<8;j++){
    s[w*1024 + l*16 + j]     = o0[j];
    s[w*1024 + l*16 + 8 + j] = o1[j];
  }
  if (l == 0){ s[4096 + w*2 + 0] = K0; s[4096 + w*2 + 1] = K1; }
  __syncthreads();
  float KT0 = s[4096+0]+s[4096+2]+s[4096+4]+s[4096+6];
  float KT1 = s[4096+1]+s[4096+3]+s[4096+5]+s[4096+7];
#pragma unroll
  for (int it2=0; it2<4; it2++){
    int e = t + it2*256;               // 0..1023
    int slot = e >> 4, comp = e & 15;
    int scg2 = slot & 3, srow = slot >> 2;
    int out = comp >> 3, j = comp & 7;
    float v = s[0*1024 + slot*16 + comp] + s[1*1024 + slot*16 + comp]
            + s[2*1024 + slot*16 + comp] + s[3*1024 + slot*16 + comp];
    v += (out ? KT1 : KT0);
    int px = X0 + scg2*8 + j, py = Y0 + srow;
    offpart[(((size_t)cg*NIMG + n)*HW + (size_t)py*WWID + px)*2 + out] = v;
  }
}

// ============ finalize: sum 4 offset partials -> clamp -> pixel coords. grid (N*HW/256).
__global__ __launch_bounds__(256) void k_samp_fin(const float* __restrict__ offpart,
                                                  float* __restrict__ samp){
  int e = blockIdx.x*256 + threadIdx.x;
  int n = e / HW, p = e - n*HW;
  int py = p / WWID, px = p - py*WWID;
  float oy = 0.f, ox = 0.f;
#pragma unroll
  for (int g=0; g<4; g++){
    float2 v = *(const float2*)(offpart + (((size_t)g*NIMG + n)*HW + p)*2);
    oy += v.x; ox += v.y;
  }
  const float k2 = 2.0f/351.0f;
  float ry = (0.5f+(float)py)*k2 - 1.0f, rx = (0.5f+(float)px)*k2 - 1.0f;
  float pyc = fminf(fmaxf(oy+ry,-0.12f),0.12f);
  float pxc = fminf(fmaxf(ox+rx,-0.12f),0.12f);
  float2 o; o.x = (pxc+1.f)*0.5f*351.f; o.y = (pyc+1.f)*0.5f*351.f;
  *(float2*)(samp + (size_t)e*2) = o;
}

// ============ routing: logits row + top-4 indices (order-only; winsums are unscaled means).
__global__ __launch_bounds__(64) void k_routing(const float* __restrict__ qwin,
                                               const float* __restrict__ kwin,
                                               int* __restrict__ topidx){
  __shared__ float lg[128];
  const int p = blockIdx.x, n = blockIdx.y, l = threadIdx.x;
  const float* qr = qwin + ((size_t)n*121 + p)*128;
  const float* kb = kwin + (size_t)n*121*128;
  float a0 = 0.f, a1 = 0.f;
  const bool has1 = (l + 64) < 121;
  for (int c=0;c<128;c++){
    float qv = qr[c];
    a0 += qv * kb[(size_t)l*128 + c];
    if (has1) a1 += qv * kb[(size_t)(l+64)*128 + c];
  }
  lg[l] = a0;
  lg[64+l] = has1 ? a1 : -3.0e38f;
  __syncthreads();
  if (l == 0){
    for (int j=0;j<4;j++){
      float best = -3.0e38f; int bi = 0;
      for (int i=0;i<121;i++){ if (lg[i] > best){ best = lg[i]; bi = i; } }
      lg[bi] = -3.0e38f;
      topidx[((size_t)n*121 + p)*4 + j] = bi;
    }
  }
}

// ============ windowed attention. grid (121, N, 4 heads), block 256. 2 px/lane.
// kvd2 has two half-cell maxes per cell -> fold with fmaxf while staging to LDS.
__global__ __launch_bounds__(256) void k_attention(const float* __restrict__ q,
                                                   const float* __restrict__ kvd2,
                                                   const int* __restrict__ topidx,
                                                   float* __restrict__ out){
  __shared__ float ks[64*32];
  __shared__ float vs[64*32];
  __shared__ int tix[4];
  const int p = blockIdx.x, n = blockIdx.y, h = blockIdx.z;
  const int t = threadIdx.x;
  if (t < 4) tix[t] = topidx[((size_t)n*121 + p)*4 + t];
  __syncthreads();
#pragma unroll
  for (int i=0;i<8;i++){
    int e = t + i*256;
    int d = e & 31, k = e >> 5;
    const float* kr = kvd2 + ((((size_t)(n*121) + tix[k>>4])*16 + (k & 15))*2)*256;
    ks[k*32 + d] = fmaxf(kr[h*32 + d],       kr[256 + h*32 + d]);
    vs[k*32 + d] = fmaxf(kr[128 + h*32 + d], kr[384 + h*32 + d]);
  }
  __syncthreads();
  const int py0 = (p/11)*32, px0 = (p%11)*32;
  const int wv = t >> 6, l = t & 63;
  const float* qh = q + ((size_t)n*C128 + h*32)*HW;
  float* oh = out + ((size_t)n*C128 + h*32)*HW;
  for (int it=0; it<2; it++){
    int pxa = it*512 + wv*128 + l;
    int pxb = pxa + 64;
    size_t offa = (size_t)(py0 + (pxa>>5))*WWID + px0 + (pxa&31);
    size_t offb = (size_t)(py0 + (pxb>>5))*WWID + px0 + (pxb&31);
    float qa[32], qb[32], oa[32], ob[32];
#pragma unroll
    for (int d=0; d<32; d++){
      qa[d] = qh[(size_t)d*HW + offa] * SCALE_F;
      qb[d] = qh[(size_t)d*HW + offb] * SCALE_F;
      oa[d] = 0.f; ob[d] = 0.f;
    }
    float suma = 0.f, sumb = 0.f;
    for (int k=0; k<64; k++){
      const float4* kk4 = (const float4*)(ks + k*32);
      float da = 0.f, db = 0.f;
#pragma unroll
      for (int d4=0; d4<8; d4++){
        float4 kk = kk4[d4];
        da += qa[d4*4+0]*kk.x + qa[d4*4+1]*kk.y + qa[d4*4+2]*kk.z + qa[d4*4+3]*kk.w;
        db += qb[d4*4+0]*kk.x + qb[d4*4+1]*kk.y + qb[d4*4+2]*kk.z + qb[d4*4+3]*kk.w;
      }
      float pa = __expf(da), pb = __expf(db);
      suma += pa; sumb += pb;
      const float4* vv4 = (const float4*)(vs + k*32);
#pragma unroll
      for (int d4=0; d4<8; d4++){
        float4 vvv = vv4[d4];
        oa[d4*4+0] += pa*vvv.x; oa[d4*4+1] += pa*vvv.y; oa[d4*4+2] += pa*vvv.z; oa[d4*4+3] += pa*vvv.w;
        ob[d4*4+0] += pb*vvv.x; ob[d4*4+1] += pb*vvv.y; ob[d4*4+2] += pb*vvv.z; ob[d4*4+3] += pb*vvv.w;
      }
    }
    float ia = 1.0f/suma, ib2 = 1.0f/sumb;
#pragma unroll
    for (int d=0; d<32; d++){
      oh[(size_t)d*HW + offa] = oa[d]*ia;
      oh[(size_t)d*HW + offb] = ob[d]*ib2;
    }
  }
}

// ============ sec: depthwise 3x3 over V-half of kv, added into out. grid (121 tiles, C, N).
__global__ __launch_bounds__(256) void k_sec_add(const float* __restrict__ kv,
                                                 const float* __restrict__ secw,
                                                 const float* __restrict__ secb,
                                                 float* __restrict__ out){
  __shared__ float s[34*34];
  const int t = threadIdx.x;
  const int bx = blockIdx.x, c = blockIdx.y, n = blockIdx.z;
  const int X0 = (bx % 11)*32, Y0 = (bx / 11)*32;
  const float* src = kv + ((size_t)n*256 + 128 + c)*HW;
  for (int e = t; e < 1156; e += 256){
    int row = e / 34;
    int col = e - row*34;
    int gr = Y0 - 1 + row, gc = X0 - 1 + col;
    s[e] = (gr >= 0 && gr < HH && gc >= 0 && gc < WWID) ? src[gr*WWID + gc] : 0.f;
  }
  __syncthreads();
  const int tx = (t & 7)*4, ty = t >> 3;
  float w[9];
#pragma unroll
  for (int i=0;i<9;i++) w[i] = secw[c*9 + i];
  float4 r = make_float4(0.f,0.f,0.f,0.f);
#pragma unroll
  for (int kr=0; kr<3; kr++){
    const float* row = s + (ty + kr)*34 + tx;
    float a0=row[0],a1=row[1],a2=row[2],a3=row[3],a4=row[4],a5=row[5];
    float w0=w[kr*3], w1=w[kr*3+1], w2=w[kr*3+2];
    r.x += w0*a0 + w1*a1 + w2*a2;
    r.y += w0*a1 + w1*a2 + w2*a3;
    r.z += w0*a2 + w1*a3 + w2*a4;
    r.w += w0*a3 + w1*a4 + w2*a5;
  }
  float bb = secb[c];
  float* op = out + ((size_t)n*C128 + c)*HW + (size_t)(Y0+ty)*WWID + X0 + tx;
  float4 cur = *(float4*)op;
  cur.x += r.x + bb; cur.y += r.y + bb; cur.z += r.z + bb; cur.w += r.w + bb;
  *(float4*)op = cur;
}

extern "C" void kernel_launch(void* const* d_in, const int* in_sizes, int n_in,
                              void* d_out, int out_size, void* d_ws, size_t ws_size,
                              hipStream_t stream) {
  const float* x        = (const float*)d_in[0];
  const float* q_w      = (const float*)d_in[1];
  const float* q_b      = (const float*)d_in[2];
  const float* kv_w     = (const float*)d_in[3];
  const float* kv_b     = (const float*)d_in[4];
  const float* off_dw_w = (const float*)d_in[5];
  const float* off_dw_b = (const float*)d_in[6];
  const float* off_bn_g = (const float*)d_in[7];
  const float* off_bn_b = (const float*)d_in[8];
  const float* off_pw_w = (const float*)d_in[9];
  const float* sec_w    = (const float*)d_in[10];
  const float* sec_b    = (const float*)d_in[11];
  float* outp = (float*)d_out;

  float* qbuf  = (float*)d_ws;                               // N*128*HW
  float* kvbuf = qbuf  + (size_t)NIMG*C128*HW;               // N*256*HW
  float* samp  = kvbuf + (size_t)NIMG*256*HW;                // N*HW*2
  float* qwin  = samp  + (size_t)NIMG*HW*2;                  // N*121*128 (zeroed)
  float* kwin  = qwin  + (size_t)NIMG*121*128;               // N*121*128 (zeroed)
  float* kvd2  = kwin  + (size_t)NIMG*121*128;               // N*121*16*2*256 (all slots stored)
  int*   tidx  = (int*)(kvd2 + (size_t)NIMG*121*16*2*256);   // N*121*4
  _Float16* wfq  = (_Float16*)(tidx + NIMG*121*4);           // 16384 f16
  _Float16* wfkv = wfq + 16384;                              // 32768 f16
  // offpart aliases the head of kvbuf (7.9 MB of 254 MB): fully written by k_offset_part,
  // consumed by k_samp_fin, both before conv64 writes kvbuf. No footprint growth.
  float* offpart = kvbuf;                                    // 4*N*HW*2

  hipMemsetAsync(qwin, 0, (size_t)NIMG*121*128*2*4, stream);

  k_wprep<<<dim3(8), 256, 0, stream>>>(q_w, wfq, 8);
  k_wprep<<<dim3(16), 256, 0, stream>>>(kv_w, wfkv, 16);
  k_conv_mfma<32, false, true, false><<<dim3(88*22, 1, NIMG), 256, 0, stream>>>(
      x, nullptr, wfq, q_b, qbuf, qwin, nullptr);
  k_offset_part<<<dim3(11, 22, NIMG*4), 256, 0, stream>>>(
      qbuf, off_dw_w, off_dw_b, off_bn_g, off_bn_b, off_pw_w, offpart);
  k_samp_fin<<<dim3(NIMG*HW/256), 256, 0, stream>>>(offpart, samp);
  k_conv_mfma<64, true, true, true><<<dim3(88*22, 1, NIMG), 256, 0, stream>>>(
      x, samp, wfkv, kv_b, kvbuf, kwin, kvd2);
  k_routing<<<dim3(121, NIMG), 64, 0, stream>>>(qwin, kwin, tidx);
  k_attention<<<dim3(121, NIMG, 4), 256, 0, stream>>>(qbuf, kvd2, tidx, outp);
  k_sec_add<<<dim3(121, 128, NIMG), 256, 0, stream>>>(kvbuf, sec_w, sec_b, outp);
}

// Round 4
// 726.683 us; speedup vs baseline: 1.3507x; 1.1332x over previous
//
#include <hip/hip_runtime.h>

#define HH 352
#define WWID 352
#define HW 123904
#define NIMG 2
#define C128 128
#define SCALE_F 0.08838834764831845f

typedef _Float16 f16x8 __attribute__((ext_vector_type(8)));
typedef _Float16 f16x4 __attribute__((ext_vector_type(4)));
typedef float f32x4 __attribute__((ext_vector_type(4)));

__device__ __forceinline__ float silu_f(float v){ return v / (1.0f + __expf(-v)); }

// ============ weight pre-swizzle into A-fragment order for mfma_f32_16x16x32_f16.
__global__ __launch_bounds__(256) void k_wprep(const float* __restrict__ W,
                                               _Float16* __restrict__ Wf, int nct){
  int e = blockIdx.x*256 + threadIdx.x;
  if (e >= nct*256) return;
  int l = e & 63, kc = (e>>6)&3, ct = e>>8;
  const float* src = W + (size_t)(ct*16 + (l&15))*128 + kc*32 + (l>>4)*8;
  f16x8 pk;
#pragma unroll
  for (int j=0;j<8;j++) pk[j] = (_Float16)src[j];
  *(f16x8*)(Wf + (size_t)e*8) = pk;
}

// ============ 1x1 conv + silu via fp16 MFMA. Block covers a 4-row x 16-col tile.
//  FUSEW: full-tile sum per co -> 1 atomicAdd per tile
//  FUSEP: half-cell (4x8) max -> plain store into kvd2 (folded by k_attention)
template<int COW, bool SAMP, bool FUSEW, bool FUSEP>
__global__ __launch_bounds__(256) void k_conv_mfma(const float* __restrict__ X,
                                                   const float* __restrict__ samp,
                                                   const _Float16* __restrict__ Wf,
                                                   const float* __restrict__ B,
                                                   float* __restrict__ O,
                                                   float* __restrict__ winsum,
                                                   float* __restrict__ kvd2){
  constexpr int Cout = COW*4;
  constexpr int MT = COW/16;
  __shared__ _Float16 Xs[16*64*8];
  __shared__ int ibs[64];
  __shared__ float4 wls[64];
  const int t = threadIdx.x;
  const int bx = blockIdx.x;
  const int ty4 = (bx/22)*4, tx16 = (bx - (bx/22)*22)*16;   // 88 x 22 tiles
  const int n = blockIdx.z;
  const int wv = t>>6, l = t&63;
  const float* Xn = X + (size_t)n*C128*HW;
  if (SAMP){
    if (t < 64){
      int fr = ty4 + (t>>4), fc = tx16 + (t&15);
      size_t si = ((size_t)n*HW + (size_t)fr*WWID + fc)*2;
      float gx = samp[si + 0];
      float gy = samp[si + 1];
      float x0f = floorf(gx), y0f = floorf(gy);
      int x0 = (int)x0f, y0 = (int)y0f;  // CLAMP=0.12 -> interior guaranteed
      float fx = gx - x0f, fy = gy - y0f;
      ibs[t] = y0*WWID + x0;
      wls[t] = make_float4((1.f-fx)*(1.f-fy), fx*(1.f-fy), (1.f-fx)*fy, fx*fy);
    }
    __syncthreads();
  }
  const int flatL = (ty4 + (l>>4))*WWID + tx16 + (l&15);
  int ib = 0; float4 wl = make_float4(0.f,0.f,0.f,0.f);
  if (SAMP){ ib = ibs[l]; wl = wls[l]; }
#pragma unroll
  for (int it=0; it<4; it++){
    int kb = it*4 + wv;
    f16x8 pk;
#pragma unroll
    for (int j=0;j<8;j++){
      int ci = kb*8 + j;
      float v;
      if (SAMP){
        const float* Xc = Xn + (size_t)ci*HW + ib;
        v = wl.x*Xc[0] + wl.y*Xc[1] + wl.z*Xc[WWID] + wl.w*Xc[WWID+1];
      } else {
        v = Xn[(size_t)ci*HW + flatL];
      }
      pk[j] = (_Float16)v;
    }
    *(f16x8*)(&Xs[(kb*64 + l)*8]) = pk;
  }
  __syncthreads();
  const int quad = l>>4, li = l&15;
  f32x4 acc[MT][4];
#pragma unroll
  for (int m=0;m<MT;m++)
#pragma unroll
    for (int nt=0;nt<4;nt++){ acc[m][nt][0]=0.f; acc[m][nt][1]=0.f; acc[m][nt][2]=0.f; acc[m][nt][3]=0.f; }
  const _Float16* Wfw = Wf + (size_t)(wv*MT)*4*64*8;
#pragma unroll
  for (int kc=0; kc<4; kc++){
    f16x8 b[4];
#pragma unroll
    for (int nt=0; nt<4; nt++)
      b[nt] = *(const f16x8*)(&Xs[((kc*4 + quad)*64 + nt*16 + li)*8]);
    f16x8 a[MT];
#pragma unroll
    for (int m=0;m<MT;m++)
      a[m] = *(const f16x8*)(Wfw + (size_t)((m*4 + kc)*64 + l)*8);
#pragma unroll
    for (int m=0;m<MT;m++)
#pragma unroll
      for (int nt=0;nt<4;nt++)
        acc[m][nt] = __builtin_amdgcn_mfma_f32_16x16x32_f16(a[m], b[nt], acc[m][nt], 0, 0, 0);
  }
  // epilogue: bias+silu, store, fused window reductions (atomicMax-free).
  const int p = (ty4>>5)*11 + (tx16>>5);
#pragma unroll
  for (int m=0;m<MT;m++){
    int cob = wv*COW + m*16 + quad*4;
#pragma unroll
    for (int r=0;r<4;r++){
      int co = cob + r;
      float bb = B[co];
      float* Op = O + ((size_t)n*Cout + co)*HW + (size_t)ty4*WWID + tx16 + li;
      float ys[4];
#pragma unroll
      for (int nt=0;nt<4;nt++){
        float y = silu_f(acc[m][nt][r] + bb);
        ys[nt] = y;
        Op[nt*WWID] = y;
      }
      if (FUSEW && co < 128){
        float ssum = ys[0] + ys[1] + ys[2] + ys[3];
        ssum += __shfl_xor(ssum,1); ssum += __shfl_xor(ssum,2);
        ssum += __shfl_xor(ssum,4); ssum += __shfl_xor(ssum,8);
        if (li == 0)
          atomicAdd(winsum + ((size_t)n*121 + p)*128 + co, ssum);
      }
      if (FUSEP){
        float mx = fmaxf(fmaxf(ys[0],ys[1]), fmaxf(ys[2],ys[3]));
        mx = fmaxf(mx, __shfl_xor(mx,1));
        mx = fmaxf(mx, __shfl_xor(mx,2));
        mx = fmaxf(mx, __shfl_xor(mx,4));
        if ((li & 7) == 0){
          int cell = ((ty4>>3)&3)*4 + ((tx16>>3)&3) + (li>>3);
          int vh = (ty4>>2)&1;
          kvd2[((((size_t)n*121 + p)*16 + cell)*2 + vh)*256 + co] = mx;
        }
      }
    }
  }
}

// ============ offset path v2: 8 px/thread sliding window, wave-uniform channel,
// atomic-free partial output. grid (11,22,N*4) with XCD-chunked swizzle, block 256.
__global__ __launch_bounds__(256) void k_offset_part(const float* __restrict__ q,
                                                     const float* __restrict__ dww,
                                                     const float* __restrict__ dwb,
                                                     const float* __restrict__ bng,
                                                     const float* __restrict__ bnb,
                                                     const float* __restrict__ pw,
                                                     float* __restrict__ offpart){
  __shared__ float s[4224];   // 4 ch x 1056 (24 x 44)
  const int t = threadIdx.x;
  int id = blockIdx.x + 11*(blockIdx.y + 22*blockIdx.z);
  int lid = (id & 7)*242 + (id >> 3);
  int bx = lid % 11; int rest = lid / 11;
  int by = rest % 22; int zz = rest / 22;
  const int X0 = bx*32, Y0 = by*16;
  const int n = zz >> 2, cg = zz & 3, c0 = cg*32;
  const int w = __builtin_amdgcn_readfirstlane(t >> 6);   // wave id = channel lane
  const int l = t & 63;
  const int cg2 = l & 3, rowi = l >> 2;                   // 4 col-groups x 16 rows
  const float inv = 1.0f / sqrtf(1.0f + 1e-5f);
  const float* qn = q + (size_t)n*C128*HW;
  float o0[8], o1[8];
#pragma unroll
  for (int j=0;j<8;j++){ o0[j]=0.f; o1[j]=0.f; }
  float K0 = 0.f, K1 = 0.f;
  float pf[17];
  auto issue = [&](int stage){
    int cbase = c0 + stage*4;
#pragma unroll
    for (int i=0;i<17;i++){
      if (i == 16 && t >= 128) continue;   // e < 4224
      int e = t + i*256;
      int ch = e/1056, idx = e - ch*1056;
      int rr = idx/44, cc = idx - rr*44;
      int gr = Y0 - 4 + rr, gc = X0 - 4 + cc;
      float v = 0.f;
      if (cc < 40 && gr>=0 && gr<HH && gc>=0 && gc<WWID)
        v = qn[(size_t)(cbase+ch)*HW + gr*WWID + gc];
      pf[i] = v;
    }
  };
  issue(0);
  for (int stage=0; stage<8; stage++){
    __syncthreads();
#pragma unroll
    for (int i=0;i<17;i++){
      if (i == 16 && t >= 128) continue;
      s[t + i*256] = pf[i];
    }
    __syncthreads();
    if (stage < 7) issue(stage+1);
    const int c = c0 + stage*4 + w;
    const float* wc = dww + c*81;            // wave-uniform -> s_load weights
    const float* scp = s + w*1056 + rowi*44 + cg2*8;
    float sum[8];
#pragma unroll
    for (int j=0;j<8;j++) sum[j]=0.f;
#pragma unroll
    for (int r=0;r<9;r++){
      float f[16];
      const float4* s4 = (const float4*)(scp + r*44);
#pragma unroll
      for (int m2=0;m2<4;m2++){
        float4 v4 = s4[m2];
        f[4*m2]=v4.x; f[4*m2+1]=v4.y; f[4*m2+2]=v4.z; f[4*m2+3]=v4.w;
      }
#pragma unroll
      for (int k=0;k<9;k++){
        float wv = wc[r*9+k];
#pragma unroll
        for (int j=0;j<8;j++) sum[j] += wv * f[j+k];
      }
    }
    float g = inv*bng[c], bet = bnb[c], db = dwb[c];
    float p0c = pw[c], p1c = pw[C128+c];
    float A0 = p0c*g, A1 = p1c*g;
    float Cc = g*db + bet;
    K0 += p0c*Cc; K1 += p1c*Cc;
#pragma unroll
    for (int j=0;j<8;j++){ o0[j] += A0*sum[j]; o1[j] += A1*sum[j]; }
  }
  __syncthreads();
#pragma unroll
  for (int j=0;j<8;j++){
    s[w*1024 + l*16 + j]     = o0[j];
    s[w*1024 + l*16 + 8 + j] = o1[j];
  }
  if (l == 0){ s[4096 + w*2 + 0] = K0; s[4096 + w*2 + 1] = K1; }
  __syncthreads();
  float KT0 = s[4096+0]+s[4096+2]+s[4096+4]+s[4096+6];
  float KT1 = s[4096+1]+s[4096+3]+s[4096+5]+s[4096+7];
#pragma unroll
  for (int it2=0; it2<4; it2++){
    int e = t + it2*256;               // 0..1023
    int slot = e >> 4, comp = e & 15;
    int scg2 = slot & 3, srow = slot >> 2;
    int out = comp >> 3, j = comp & 7;
    float v = s[0*1024 + slot*16 + comp] + s[1*1024 + slot*16 + comp]
            + s[2*1024 + slot*16 + comp] + s[3*1024 + slot*16 + comp];
    v += (out ? KT1 : KT0);
    int px = X0 + scg2*8 + j, py = Y0 + srow;
    offpart[(((size_t)cg*NIMG + n)*HW + (size_t)py*WWID + px)*2 + out] = v;
  }
}

// ============ finalize: sum 4 offset partials -> clamp -> pixel coords. grid (N*HW/256).
__global__ __launch_bounds__(256) void k_samp_fin(const float* __restrict__ offpart,
                                                  float* __restrict__ samp){
  int e = blockIdx.x*256 + threadIdx.x;
  int n = e / HW, p = e - n*HW;
  int py = p / WWID, px = p - py*WWID;
  float oy = 0.f, ox = 0.f;
#pragma unroll
  for (int g=0; g<4; g++){
    float2 v = *(const float2*)(offpart + (((size_t)g*NIMG + n)*HW + p)*2);
    oy += v.x; ox += v.y;
  }
  const float k2 = 2.0f/351.0f;
  float ry = (0.5f+(float)py)*k2 - 1.0f, rx = (0.5f+(float)px)*k2 - 1.0f;
  float pyc = fminf(fmaxf(oy+ry,-0.12f),0.12f);
  float pxc = fminf(fmaxf(ox+rx,-0.12f),0.12f);
  float2 o; o.x = (pxc+1.f)*0.5f*351.f; o.y = (pyc+1.f)*0.5f*351.f;
  *(float2*)(samp + (size_t)e*2) = o;
}

// ============ routing: logits row + top-4 indices (order-only; winsums are unscaled means).
__global__ __launch_bounds__(64) void k_routing(const float* __restrict__ qwin,
                                               const float* __restrict__ kwin,
                                               int* __restrict__ topidx){
  __shared__ float lg[128];
  const int p = blockIdx.x, n = blockIdx.y, l = threadIdx.x;
  const float* qr = qwin + ((size_t)n*121 + p)*128;
  const float* kb = kwin + (size_t)n*121*128;
  float a0 = 0.f, a1 = 0.f;
  const bool has1 = (l + 64) < 121;
  for (int c=0;c<128;c++){
    float qv = qr[c];
    a0 += qv * kb[(size_t)l*128 + c];
    if (has1) a1 += qv * kb[(size_t)(l+64)*128 + c];
  }
  lg[l] = a0;
  lg[64+l] = has1 ? a1 : -3.0e38f;
  __syncthreads();
  if (l == 0){
    for (int j=0;j<4;j++){
      float best = -3.0e38f; int bi = 0;
      for (int i=0;i<121;i++){ if (lg[i] > best){ best = lg[i]; bi = i; } }
      lg[bi] = -3.0e38f;
      topidx[((size_t)n*121 + p)*4 + j] = bi;
    }
  }
}

// ============ windowed attention via fp16 MFMA. grid (121, N, 16), z = qt*4 + h.
// Per block: one head, one quarter-window (256 px). S = K·Q (A=K rows=keys, B=Q cols=px),
// wave-level softmax (16 local + shfl_xor 16/32), P packed f16x4 -> per-wave LDS,
// O = V^T·P (A=V^T rows=dims, B=P cols=px). Same fragment layout as k_conv_mfma/k_wprep.
__global__ __launch_bounds__(256) void k_attention(const float* __restrict__ q,
                                                   const float* __restrict__ kvd2,
                                                   const int* __restrict__ topidx,
                                                   float* __restrict__ out){
  __shared__ _Float16 Ks[64*40];      // [key][dim], stride 40 (2-way bank alias = free)
  __shared__ _Float16 Vs[32*72];      // [dim][key], stride 72
  __shared__ _Float16 Ps[4*16*72];    // per-wave [px][key], stride 72
  __shared__ int tix[4];
  const int p = blockIdx.x, n = blockIdx.y;
  const int h = blockIdx.z & 3, qt = blockIdx.z >> 2;
  const int t = threadIdx.x;
  if (t < 4) tix[t] = topidx[((size_t)n*121 + p)*4 + t];
  __syncthreads();
#pragma unroll
  for (int i=0;i<8;i++){
    int e = t + i*256;           // 0..2047
    int d = e & 31, k = e >> 5;
    const float* kr = kvd2 + ((((size_t)(n*121) + tix[k>>4])*16 + (k & 15))*2)*256;
    float kk = fmaxf(kr[h*32 + d],       kr[256 + h*32 + d]);
    float vv = fmaxf(kr[128 + h*32 + d], kr[384 + h*32 + d]);
    Ks[k*40 + d] = (_Float16)kk;
    Vs[d*72 + k] = (_Float16)vv;
  }
  __syncthreads();
  const int py0 = (p/11)*32, px0 = (p%11)*32;
  const int w = t >> 6, l = t & 63;
  const int li = l & 15, qd = l >> 4;
  const float* qh = q + ((size_t)n*C128 + h*32)*HW;
  float* oh = out + ((size_t)n*C128 + h*32)*HW;
  _Float16* Pw = Ps + w*16*72;
  for (int it=0; it<4; it++){
    int g = qt*16 + it*4 + w;           // px group 0..63: row = g>>1, half = g&1
    size_t base = (size_t)(py0 + (g>>1))*WWID + px0 + (g&1)*16 + li;
    // Q fragment (B): col=px=li, k=dim qd*8+j; scale folded pre-fp16.
    f16x8 qa;
#pragma unroll
    for (int j=0;j<8;j++)
      qa[j] = (_Float16)(qh[(size_t)(qd*8+j)*HW + base] * SCALE_F);
    // S = K·Q: 4 key-tiles of 16. Lane holds keys nt*16 + qd*4 + r for px=li.
    f32x4 S[4];
#pragma unroll
    for (int nt=0;nt<4;nt++){
      f16x8 ka = *(const f16x8*)(Ks + (nt*16 + li)*40 + qd*8);
      f32x4 z; z[0]=0.f; z[1]=0.f; z[2]=0.f; z[3]=0.f;
      S[nt] = __builtin_amdgcn_mfma_f32_16x16x32_f16(ka, qa, z, 0, 0, 0);
    }
    // softmax over 64 keys (per px; quads l, l+16, l+32, l+48 share px)
    float m = -3.0e38f;
#pragma unroll
    for (int nt=0;nt<4;nt++)
#pragma unroll
      for (int r=0;r<4;r++) m = fmaxf(m, S[nt][r]);
    m = fmaxf(m, __shfl_xor(m, 16));
    m = fmaxf(m, __shfl_xor(m, 32));
    float sum = 0.f;
#pragma unroll
    for (int nt=0;nt<4;nt++){
      f16x4 pk;
#pragma unroll
      for (int r=0;r<4;r++){
        float e = __expf(S[nt][r] - m);
        sum += e;
        pk[r] = (_Float16)e;
      }
      *(f16x4*)(Pw + li*72 + nt*16 + qd*4) = pk;   // same-wave LDS, no barrier
    }
    sum += __shfl_xor(sum, 16);
    sum += __shfl_xor(sum, 32);
    float inv = 1.0f / sum;
    // O = V^T·P: 2 dim-tiles x 2 key-chunks
    f32x4 a0, a1;
    a0[0]=0.f;a0[1]=0.f;a0[2]=0.f;a0[3]=0.f;
    a1[0]=0.f;a1[1]=0.f;a1[2]=0.f;a1[3]=0.f;
#pragma unroll
    for (int c=0;c<2;c++){
      f16x8 pb  = *(const f16x8*)(Pw + li*72        + c*32 + qd*8);
      f16x8 va0 = *(const f16x8*)(Vs + li*72        + c*32 + qd*8);
      f16x8 va1 = *(const f16x8*)(Vs + (16+li)*72   + c*32 + qd*8);
      a0 = __builtin_amdgcn_mfma_f32_16x16x32_f16(va0, pb, a0, 0, 0, 0);
      a1 = __builtin_amdgcn_mfma_f32_16x16x32_f16(va1, pb, a1, 0, 0, 0);
    }
    // D: col=px=li (inv lives in-lane), row=dim=qd*4+r (+16 for a1)
#pragma unroll
    for (int r=0;r<4;r++){
      oh[(size_t)(qd*4+r)*HW + base]        = a0[r]*inv;
      oh[(size_t)(16+qd*4+r)*HW + base]     = a1[r]*inv;
    }
  }
}

// ============ sec: depthwise 3x3 over V-half of kv, added into out. grid (121 tiles, C, N).
__global__ __launch_bounds__(256) void k_sec_add(const float* __restrict__ kv,
                                                 const float* __restrict__ secw,
                                                 const float* __restrict__ secb,
                                                 float* __restrict__ out){
  __shared__ float s[34*34];
  const int t = threadIdx.x;
  const int bx = blockIdx.x, c = blockIdx.y, n = blockIdx.z;
  const int X0 = (bx % 11)*32, Y0 = (bx / 11)*32;
  const float* src = kv + ((size_t)n*256 + 128 + c)*HW;
  for (int e = t; e < 1156; e += 256){
    int row = e / 34;
    int col = e - row*34;
    int gr = Y0 - 1 + row, gc = X0 - 1 + col;
    s[e] = (gr >= 0 && gr < HH && gc >= 0 && gc < WWID) ? src[gr*WWID + gc] : 0.f;
  }
  __syncthreads();
  const int tx = (t & 7)*4, ty = t >> 3;
  float w[9];
#pragma unroll
  for (int i=0;i<9;i++) w[i] = secw[c*9 + i];
  float4 r = make_float4(0.f,0.f,0.f,0.f);
#pragma unroll
  for (int kr=0; kr<3; kr++){
    const float* row = s + (ty + kr)*34 + tx;
    float a0=row[0],a1=row[1],a2=row[2],a3=row[3],a4=row[4],a5=row[5];
    float w0=w[kr*3], w1=w[kr*3+1], w2=w[kr*3+2];
    r.x += w0*a0 + w1*a1 + w2*a2;
    r.y += w0*a1 + w1*a2 + w2*a3;
    r.z += w0*a2 + w1*a3 + w2*a4;
    r.w += w0*a3 + w1*a4 + w2*a5;
  }
  float bb = secb[c];
  float* op = out + ((size_t)n*C128 + c)*HW + (size_t)(Y0+ty)*WWID + X0 + tx;
  float4 cur = *(float4*)op;
  cur.x += r.x + bb; cur.y += r.y + bb; cur.z += r.z + bb; cur.w += r.w + bb;
  *(float4*)op = cur;
}

extern "C" void kernel_launch(void* const* d_in, const int* in_sizes, int n_in,
                              void* d_out, int out_size, void* d_ws, size_t ws_size,
                              hipStream_t stream) {
  const float* x        = (const float*)d_in[0];
  const float* q_w      = (const float*)d_in[1];
  const float* q_b      = (const float*)d_in[2];
  const float* kv_w     = (const float*)d_in[3];
  const float* kv_b     = (const float*)d_in[4];
  const float* off_dw_w = (const float*)d_in[5];
  const float* off_dw_b = (const float*)d_in[6];
  const float* off_bn_g = (const float*)d_in[7];
  const float* off_bn_b = (const float*)d_in[8];
  const float* off_pw_w = (const float*)d_in[9];
  const float* sec_w    = (const float*)d_in[10];
  const float* sec_b    = (const float*)d_in[11];
  float* outp = (float*)d_out;

  float* qbuf  = (float*)d_ws;                               // N*128*HW
  float* kvbuf = qbuf  + (size_t)NIMG*C128*HW;               // N*256*HW
  float* samp  = kvbuf + (size_t)NIMG*256*HW;                // N*HW*2
  float* qwin  = samp  + (size_t)NIMG*HW*2;                  // N*121*128 (zeroed)
  float* kwin  = qwin  + (size_t)NIMG*121*128;               // N*121*128 (zeroed)
  float* kvd2  = kwin  + (size_t)NIMG*121*128;               // N*121*16*2*256 (all slots stored)
  int*   tidx  = (int*)(kvd2 + (size_t)NIMG*121*16*2*256);   // N*121*4
  _Float16* wfq  = (_Float16*)(tidx + NIMG*121*4);           // 16384 f16
  _Float16* wfkv = wfq + 16384;                              // 32768 f16
  // offpart aliases the head of kvbuf (7.9 MB of 254 MB): fully written by k_offset_part,
  // consumed by k_samp_fin, both before conv64 writes kvbuf. No footprint growth.
  float* offpart = kvbuf;                                    // 4*N*HW*2

  hipMemsetAsync(qwin, 0, (size_t)NIMG*121*128*2*4, stream);

  k_wprep<<<dim3(8), 256, 0, stream>>>(q_w, wfq, 8);
  k_wprep<<<dim3(16), 256, 0, stream>>>(kv_w, wfkv, 16);
  k_conv_mfma<32, false, true, false><<<dim3(88*22, 1, NIMG), 256, 0, stream>>>(
      x, nullptr, wfq, q_b, qbuf, qwin, nullptr);
  k_offset_part<<<dim3(11, 22, NIMG*4), 256, 0, stream>>>(
      qbuf, off_dw_w, off_dw_b, off_bn_g, off_bn_b, off_pw_w, offpart);
  k_samp_fin<<<dim3(NIMG*HW/256), 256, 0, stream>>>(offpart, samp);
  k_conv_mfma<64, true, true, true><<<dim3(88*22, 1, NIMG), 256, 0, stream>>>(
      x, samp, wfkv, kv_b, kvbuf, kwin, kvd2);
  k_routing<<<dim3(121, NIMG), 64, 0, stream>>>(qwin, kwin, tidx);
  k_attention<<<dim3(121, NIMG, 16), 256, 0, stream>>>(qbuf, kvd2, tidx, outp);
  k_sec_add<<<dim3(121, 128, NIMG), 256, 0, stream>>>(kvbuf, sec_w, sec_b, outp);
}

// Round 5
// 716.632 us; speedup vs baseline: 1.3697x; 1.0140x over previous
//
#include <hip/hip_runtime.h>

#define HH 352
#define WWID 352
#define HW 123904
#define NIMG 2
#define C128 128
#define SCALE_F 0.08838834764831845f

typedef _Float16 f16x8 __attribute__((ext_vector_type(8)));
typedef _Float16 f16x4 __attribute__((ext_vector_type(4)));
typedef float f32x4 __attribute__((ext_vector_type(4)));

// fast silu: v_rcp_f32 (~1 ulp) instead of IEEE divide (10-instr sequence)
__device__ __forceinline__ float silu_f(float v){
  return v * __builtin_amdgcn_rcpf(1.0f + __expf(-v));
}

// ============ weight pre-swizzle into A-fragment order for mfma_f32_16x16x32_f16.
__global__ __launch_bounds__(256) void k_wprep(const float* __restrict__ W,
                                               _Float16* __restrict__ Wf, int nct){
  int e = blockIdx.x*256 + threadIdx.x;
  if (e >= nct*256) return;
  int l = e & 63, kc = (e>>6)&3, ct = e>>8;
  const float* src = W + (size_t)(ct*16 + (l&15))*128 + kc*32 + (l>>4)*8;
  f16x8 pk;
#pragma unroll
  for (int j=0;j<8;j++) pk[j] = (_Float16)src[j];
  *(f16x8*)(Wf + (size_t)e*8) = pk;
}

// ============ 1x1 conv + silu via fp16 MFMA. Block covers a 4-row x 16-col tile.
//  FUSEW: full-tile sum per co -> 1 atomicAdd per tile
//  FUSEP: half-cell (4x8) max -> plain store into kvd2 (folded by k_attention)
// SAMP: per-thread bilinear base/weights computed directly (no LDS round-trip/barrier).
template<int COW, bool SAMP, bool FUSEW, bool FUSEP>
__global__ __launch_bounds__(256) void k_conv_mfma(const float* __restrict__ X,
                                                   const float* __restrict__ samp,
                                                   const _Float16* __restrict__ Wf,
                                                   const float* __restrict__ B,
                                                   float* __restrict__ O,
                                                   float* __restrict__ winsum,
                                                   float* __restrict__ kvd2){
  constexpr int Cout = COW*4;
  constexpr int MT = COW/16;
  __shared__ _Float16 Xs[16*64*8];
  const int t = threadIdx.x;
  const int bx = blockIdx.x;
  const int ty4 = (bx/22)*4, tx16 = (bx - (bx/22)*22)*16;   // 88 x 22 tiles
  const int n = blockIdx.z;
  const int wv = t>>6, l = t&63;
  const float* Xn = X + (size_t)n*C128*HW;
  int ib = 0; float4 wl = make_float4(0.f,0.f,0.f,0.f);
  if (SAMP){
    int fr = ty4 + (l>>4), fc = tx16 + (l&15);
    float2 sv = *(const float2*)(samp + ((size_t)n*HW + (size_t)fr*WWID + fc)*2);
    float x0f = floorf(sv.x), y0f = floorf(sv.y);
    int x0 = (int)x0f, y0 = (int)y0f;   // CLAMP=0.12 -> interior guaranteed
    float fx = sv.x - x0f, fy = sv.y - y0f;
    ib = y0*WWID + x0;
    wl = make_float4((1.f-fx)*(1.f-fy), fx*(1.f-fy), (1.f-fx)*fy, fx*fy);
  }
  const int flatL = (ty4 + (l>>4))*WWID + tx16 + (l&15);
#pragma unroll
  for (int it=0; it<4; it++){
    int kb = it*4 + wv;
    f16x8 pk;
#pragma unroll
    for (int j=0;j<8;j++){
      int ci = kb*8 + j;
      float v;
      if (SAMP){
        const float* Xc = Xn + (size_t)ci*HW + ib;
        v = wl.x*Xc[0] + wl.y*Xc[1] + wl.z*Xc[WWID] + wl.w*Xc[WWID+1];
      } else {
        v = Xn[(size_t)ci*HW + flatL];
      }
      pk[j] = (_Float16)v;
    }
    *(f16x8*)(&Xs[(kb*64 + l)*8]) = pk;
  }
  __syncthreads();
  const int quad = l>>4, li = l&15;
  f32x4 acc[MT][4];
#pragma unroll
  for (int m=0;m<MT;m++)
#pragma unroll
    for (int nt=0;nt<4;nt++){ acc[m][nt][0]=0.f; acc[m][nt][1]=0.f; acc[m][nt][2]=0.f; acc[m][nt][3]=0.f; }
  const _Float16* Wfw = Wf + (size_t)(wv*MT)*4*64*8;
#pragma unroll
  for (int kc=0; kc<4; kc++){
    f16x8 b[4];
#pragma unroll
    for (int nt=0; nt<4; nt++)
      b[nt] = *(const f16x8*)(&Xs[((kc*4 + quad)*64 + nt*16 + li)*8]);
    f16x8 a[MT];
#pragma unroll
    for (int m=0;m<MT;m++)
      a[m] = *(const f16x8*)(Wfw + (size_t)((m*4 + kc)*64 + l)*8);
#pragma unroll
    for (int m=0;m<MT;m++)
#pragma unroll
      for (int nt=0;nt<4;nt++)
        acc[m][nt] = __builtin_amdgcn_mfma_f32_16x16x32_f16(a[m], b[nt], acc[m][nt], 0, 0, 0);
  }
  // epilogue: bias+silu, store, fused window reductions (atomicMax-free).
  const int p = (ty4>>5)*11 + (tx16>>5);
#pragma unroll
  for (int m=0;m<MT;m++){
    int cob = wv*COW + m*16 + quad*4;
#pragma unroll
    for (int r=0;r<4;r++){
      int co = cob + r;
      float bb = B[co];
      float* Op = O + ((size_t)n*Cout + co)*HW + (size_t)ty4*WWID + tx16 + li;
      float ys[4];
#pragma unroll
      for (int nt=0;nt<4;nt++){
        float y = silu_f(acc[m][nt][r] + bb);
        ys[nt] = y;
        Op[nt*WWID] = y;
      }
      if (FUSEW && co < 128){
        float ssum = ys[0] + ys[1] + ys[2] + ys[3];
        ssum += __shfl_xor(ssum,1); ssum += __shfl_xor(ssum,2);
        ssum += __shfl_xor(ssum,4); ssum += __shfl_xor(ssum,8);
        if (li == 0)
          atomicAdd(winsum + ((size_t)n*121 + p)*128 + co, ssum);
      }
      if (FUSEP){
        float mx = fmaxf(fmaxf(ys[0],ys[1]), fmaxf(ys[2],ys[3]));
        mx = fmaxf(mx, __shfl_xor(mx,1));
        mx = fmaxf(mx, __shfl_xor(mx,2));
        mx = fmaxf(mx, __shfl_xor(mx,4));
        if ((li & 7) == 0){
          int cell = ((ty4>>3)&3)*4 + ((tx16>>3)&3) + (li>>3);
          int vh = (ty4>>2)&1;
          kvd2[((((size_t)n*121 + p)*16 + cell)*2 + vh)*256 + co] = mx;
        }
      }
    }
  }
}

// ============ offset path v2: 8 px/thread sliding window, wave-uniform channel,
// atomic-free partial output. grid (11,22,N*4) with XCD-chunked swizzle, block 256.
__global__ __launch_bounds__(256) void k_offset_part(const float* __restrict__ q,
                                                     const float* __restrict__ dww,
                                                     const float* __restrict__ dwb,
                                                     const float* __restrict__ bng,
                                                     const float* __restrict__ bnb,
                                                     const float* __restrict__ pw,
                                                     float* __restrict__ offpart){
  __shared__ float s[4224];   // 4 ch x 1056 (24 x 44)
  const int t = threadIdx.x;
  int id = blockIdx.x + 11*(blockIdx.y + 22*blockIdx.z);
  int lid = (id & 7)*242 + (id >> 3);
  int bx = lid % 11; int rest = lid / 11;
  int by = rest % 22; int zz = rest / 22;
  const int X0 = bx*32, Y0 = by*16;
  const int n = zz >> 2, cg = zz & 3, c0 = cg*32;
  const int w = __builtin_amdgcn_readfirstlane(t >> 6);   // wave id = channel lane
  const int l = t & 63;
  const int cg2 = l & 3, rowi = l >> 2;                   // 4 col-groups x 16 rows
  const float inv = 1.0f / sqrtf(1.0f + 1e-5f);
  const float* qn = q + (size_t)n*C128*HW;
  float o0[8], o1[8];
#pragma unroll
  for (int j=0;j<8;j++){ o0[j]=0.f; o1[j]=0.f; }
  float K0 = 0.f, K1 = 0.f;
  float pf[17];
  auto issue = [&](int stage){
    int cbase = c0 + stage*4;
#pragma unroll
    for (int i=0;i<17;i++){
      if (i == 16 && t >= 128) continue;   // e < 4224
      int e = t + i*256;
      int ch = e/1056, idx = e - ch*1056;
      int rr = idx/44, cc = idx - rr*44;
      int gr = Y0 - 4 + rr, gc = X0 - 4 + cc;
      float v = 0.f;
      if (cc < 40 && gr>=0 && gr<HH && gc>=0 && gc<WWID)
        v = qn[(size_t)(cbase+ch)*HW + gr*WWID + gc];
      pf[i] = v;
    }
  };
  issue(0);
  for (int stage=0; stage<8; stage++){
    __syncthreads();
#pragma unroll
    for (int i=0;i<17;i++){
      if (i == 16 && t >= 128) continue;
      s[t + i*256] = pf[i];
    }
    __syncthreads();
    if (stage < 7) issue(stage+1);
    const int c = c0 + stage*4 + w;
    const float* wc = dww + c*81;            // wave-uniform -> s_load weights
    const float* scp = s + w*1056 + rowi*44 + cg2*8;
    float sum[8];
#pragma unroll
    for (int j=0;j<8;j++) sum[j]=0.f;
#pragma unroll
    for (int r=0;r<9;r++){
      float f[16];
      const float4* s4 = (const float4*)(scp + r*44);
#pragma unroll
      for (int m2=0;m2<4;m2++){
        float4 v4 = s4[m2];
        f[4*m2]=v4.x; f[4*m2+1]=v4.y; f[4*m2+2]=v4.z; f[4*m2+3]=v4.w;
      }
#pragma unroll
      for (int k=0;k<9;k++){
        float wv = wc[r*9+k];
#pragma unroll
        for (int j=0;j<8;j++) sum[j] += wv * f[j+k];
      }
    }
    float g = inv*bng[c], bet = bnb[c], db = dwb[c];
    float p0c = pw[c], p1c = pw[C128+c];
    float A0 = p0c*g, A1 = p1c*g;
    float Cc = g*db + bet;
    K0 += p0c*Cc; K1 += p1c*Cc;
#pragma unroll
    for (int j=0;j<8;j++){ o0[j] += A0*sum[j]; o1[j] += A1*sum[j]; }
  }
  __syncthreads();
#pragma unroll
  for (int j=0;j<8;j++){
    s[w*1024 + l*16 + j]     = o0[j];
    s[w*1024 + l*16 + 8 + j] = o1[j];
  }
  if (l == 0){ s[4096 + w*2 + 0] = K0; s[4096 + w*2 + 1] = K1; }
  __syncthreads();
  float KT0 = s[4096+0]+s[4096+2]+s[4096+4]+s[4096+6];
  float KT1 = s[4096+1]+s[4096+3]+s[4096+5]+s[4096+7];
#pragma unroll
  for (int it2=0; it2<4; it2++){
    int e = t + it2*256;               // 0..1023
    int slot = e >> 4, comp = e & 15;
    int scg2 = slot & 3, srow = slot >> 2;
    int out = comp >> 3, j = comp & 7;
    float v = s[0*1024 + slot*16 + comp] + s[1*1024 + slot*16 + comp]
            + s[2*1024 + slot*16 + comp] + s[3*1024 + slot*16 + comp];
    v += (out ? KT1 : KT0);
    int px = X0 + scg2*8 + j, py = Y0 + srow;
    offpart[(((size_t)cg*NIMG + n)*HW + (size_t)py*WWID + px)*2 + out] = v;
  }
}

// ============ finalize: sum 4 offset partials -> clamp -> pixel coords. grid (N*HW/256).
__global__ __launch_bounds__(256) void k_samp_fin(const float* __restrict__ offpart,
                                                  float* __restrict__ samp){
  int e = blockIdx.x*256 + threadIdx.x;
  int n = e / HW, p = e - n*HW;
  int py = p / WWID, px = p - py*WWID;
  float oy = 0.f, ox = 0.f;
#pragma unroll
  for (int g=0; g<4; g++){
    float2 v = *(const float2*)(offpart + (((size_t)g*NIMG + n)*HW + p)*2);
    oy += v.x; ox += v.y;
  }
  const float k2 = 2.0f/351.0f;
  float ry = (0.5f+(float)py)*k2 - 1.0f, rx = (0.5f+(float)px)*k2 - 1.0f;
  float pyc = fminf(fmaxf(oy+ry,-0.12f),0.12f);
  float pxc = fminf(fmaxf(ox+rx,-0.12f),0.12f);
  float2 o; o.x = (pxc+1.f)*0.5f*351.f; o.y = (pyc+1.f)*0.5f*351.f;
  *(float2*)(samp + (size_t)e*2) = o;
}

// ============ routing: logits row + top-4 indices (order-only; winsums are unscaled means).
__global__ __launch_bounds__(64) void k_routing(const float* __restrict__ qwin,
                                               const float* __restrict__ kwin,
                                               int* __restrict__ topidx){
  __shared__ float lg[128];
  const int p = blockIdx.x, n = blockIdx.y, l = threadIdx.x;
  const float* qr = qwin + ((size_t)n*121 + p)*128;
  const float* kb = kwin + (size_t)n*121*128;
  float a0 = 0.f, a1 = 0.f;
  const bool has1 = (l + 64) < 121;
  for (int c=0;c<128;c++){
    float qv = qr[c];
    a0 += qv * kb[(size_t)l*128 + c];
    if (has1) a1 += qv * kb[(size_t)(l+64)*128 + c];
  }
  lg[l] = a0;
  lg[64+l] = has1 ? a1 : -3.0e38f;
  __syncthreads();
  if (l == 0){
    for (int j=0;j<4;j++){
      float best = -3.0e38f; int bi = 0;
      for (int i=0;i<121;i++){ if (lg[i] > best){ best = lg[i]; bi = i; } }
      lg[bi] = -3.0e38f;
      topidx[((size_t)n*121 + p)*4 + j] = bi;
    }
  }
}

// ============ windowed attention via fp16 MFMA. grid (121, N, 16), z = qt*4 + h.
__global__ __launch_bounds__(256) void k_attention(const float* __restrict__ q,
                                                   const float* __restrict__ kvd2,
                                                   const int* __restrict__ topidx,
                                                   float* __restrict__ out){
  __shared__ _Float16 Ks[64*40];      // [key][dim], stride 40 (2-way bank alias = free)
  __shared__ _Float16 Vs[32*72];      // [dim][key], stride 72
  __shared__ _Float16 Ps[4*16*72];    // per-wave [px][key], stride 72
  __shared__ int tix[4];
  const int p = blockIdx.x, n = blockIdx.y;
  const int h = blockIdx.z & 3, qt = blockIdx.z >> 2;
  const int t = threadIdx.x;
  if (t < 4) tix[t] = topidx[((size_t)n*121 + p)*4 + t];
  __syncthreads();
#pragma unroll
  for (int i=0;i<8;i++){
    int e = t + i*256;           // 0..2047
    int d = e & 31, k = e >> 5;
    const float* kr = kvd2 + ((((size_t)(n*121) + tix[k>>4])*16 + (k & 15))*2)*256;
    float kk = fmaxf(kr[h*32 + d],       kr[256 + h*32 + d]);
    float vv = fmaxf(kr[128 + h*32 + d], kr[384 + h*32 + d]);
    Ks[k*40 + d] = (_Float16)kk;
    Vs[d*72 + k] = (_Float16)vv;
  }
  __syncthreads();
  const int py0 = (p/11)*32, px0 = (p%11)*32;
  const int w = t >> 6, l = t & 63;
  const int li = l & 15, qd = l >> 4;
  const float* qh = q + ((size_t)n*C128 + h*32)*HW;
  float* oh = out + ((size_t)n*C128 + h*32)*HW;
  _Float16* Pw = Ps + w*16*72;
  for (int it=0; it<4; it++){
    int g = qt*16 + it*4 + w;           // px group 0..63: row = g>>1, half = g&1
    size_t base = (size_t)(py0 + (g>>1))*WWID + px0 + (g&1)*16 + li;
    f16x8 qa;
#pragma unroll
    for (int j=0;j<8;j++)
      qa[j] = (_Float16)(qh[(size_t)(qd*8+j)*HW + base] * SCALE_F);
    f32x4 S[4];
#pragma unroll
    for (int nt=0;nt<4;nt++){
      f16x8 ka = *(const f16x8*)(Ks + (nt*16 + li)*40 + qd*8);
      f32x4 z; z[0]=0.f; z[1]=0.f; z[2]=0.f; z[3]=0.f;
      S[nt] = __builtin_amdgcn_mfma_f32_16x16x32_f16(ka, qa, z, 0, 0, 0);
    }
    float m = -3.0e38f;
#pragma unroll
    for (int nt=0;nt<4;nt++)
#pragma unroll
      for (int r=0;r<4;r++) m = fmaxf(m, S[nt][r]);
    m = fmaxf(m, __shfl_xor(m, 16));
    m = fmaxf(m, __shfl_xor(m, 32));
    float sum = 0.f;
#pragma unroll
    for (int nt=0;nt<4;nt++){
      f16x4 pk;
#pragma unroll
      for (int r=0;r<4;r++){
        float e = __expf(S[nt][r] - m);
        sum += e;
        pk[r] = (_Float16)e;
      }
      *(f16x4*)(Pw + li*72 + nt*16 + qd*4) = pk;   // same-wave LDS, no barrier
    }
    sum += __shfl_xor(sum, 16);
    sum += __shfl_xor(sum, 32);
    float inv = __builtin_amdgcn_rcpf(sum);
    f32x4 a0, a1;
    a0[0]=0.f;a0[1]=0.f;a0[2]=0.f;a0[3]=0.f;
    a1[0]=0.f;a1[1]=0.f;a1[2]=0.f;a1[3]=0.f;
#pragma unroll
    for (int c=0;c<2;c++){
      f16x8 pb  = *(const f16x8*)(Pw + li*72        + c*32 + qd*8);
      f16x8 va0 = *(const f16x8*)(Vs + li*72        + c*32 + qd*8);
      f16x8 va1 = *(const f16x8*)(Vs + (16+li)*72   + c*32 + qd*8);
      a0 = __builtin_amdgcn_mfma_f32_16x16x32_f16(va0, pb, a0, 0, 0, 0);
      a1 = __builtin_amdgcn_mfma_f32_16x16x32_f16(va1, pb, a1, 0, 0, 0);
    }
#pragma unroll
    for (int r=0;r<4;r++){
      oh[(size_t)(qd*4+r)*HW + base]        = a0[r]*inv;
      oh[(size_t)(16+qd*4+r)*HW + base]     = a1[r]*inv;
    }
  }
}

// ============ sec: depthwise 3x3 over V-half of kv, added into out. grid (121 tiles, C, N).
__global__ __launch_bounds__(256) void k_sec_add(const float* __restrict__ kv,
                                                 const float* __restrict__ secw,
                                                 const float* __restrict__ secb,
                                                 float* __restrict__ out){
  __shared__ float s[34*34];
  const int t = threadIdx.x;
  const int bx = blockIdx.x, c = blockIdx.y, n = blockIdx.z;
  const int X0 = (bx % 11)*32, Y0 = (bx / 11)*32;
  const float* src = kv + ((size_t)n*256 + 128 + c)*HW;
  for (int e = t; e < 1156; e += 256){
    int row = e / 34;
    int col = e - row*34;
    int gr = Y0 - 1 + row, gc = X0 - 1 + col;
    s[e] = (gr >= 0 && gr < HH && gc >= 0 && gc < WWID) ? src[gr*WWID + gc] : 0.f;
  }
  __syncthreads();
  const int tx = (t & 7)*4, ty = t >> 3;
  float w[9];
#pragma unroll
  for (int i=0;i<9;i++) w[i] = secw[c*9 + i];
  float4 r = make_float4(0.f,0.f,0.f,0.f);
#pragma unroll
  for (int kr=0; kr<3; kr++){
    const float* row = s + (ty + kr)*34 + tx;
    float a0=row[0],a1=row[1],a2=row[2],a3=row[3],a4=row[4],a5=row[5];
    float w0=w[kr*3], w1=w[kr*3+1], w2=w[kr*3+2];
    r.x += w0*a0 + w1*a1 + w2*a2;
    r.y += w0*a1 + w1*a2 + w2*a3;
    r.z += w0*a2 + w1*a3 + w2*a4;
    r.w += w0*a3 + w1*a4 + w2*a5;
  }
  float bb = secb[c];
  float* op = out + ((size_t)n*C128 + c)*HW + (size_t)(Y0+ty)*WWID + X0 + tx;
  float4 cur = *(float4*)op;
  cur.x += r.x + bb; cur.y += r.y + bb; cur.z += r.z + bb; cur.w += r.w + bb;
  *(float4*)op = cur;
}

extern "C" void kernel_launch(void* const* d_in, const int* in_sizes, int n_in,
                              void* d_out, int out_size, void* d_ws, size_t ws_size,
                              hipStream_t stream) {
  const float* x        = (const float*)d_in[0];
  const float* q_w      = (const float*)d_in[1];
  const float* q_b      = (const float*)d_in[2];
  const float* kv_w     = (const float*)d_in[3];
  const float* kv_b     = (const float*)d_in[4];
  const float* off_dw_w = (const float*)d_in[5];
  const float* off_dw_b = (const float*)d_in[6];
  const float* off_bn_g = (const float*)d_in[7];
  const float* off_bn_b = (const float*)d_in[8];
  const float* off_pw_w = (const float*)d_in[9];
  const float* sec_w    = (const float*)d_in[10];
  const float* sec_b    = (const float*)d_in[11];
  float* outp = (float*)d_out;

  float* qbuf  = (float*)d_ws;                               // N*128*HW
  float* kvbuf = qbuf  + (size_t)NIMG*C128*HW;               // N*256*HW
  float* samp  = kvbuf + (size_t)NIMG*256*HW;                // N*HW*2
  float* qwin  = samp  + (size_t)NIMG*HW*2;                  // N*121*128 (zeroed)
  float* kwin  = qwin  + (size_t)NIMG*121*128;               // N*121*128 (zeroed)
  float* kvd2  = kwin  + (size_t)NIMG*121*128;               // N*121*16*2*256 (all slots stored)
  int*   tidx  = (int*)(kvd2 + (size_t)NIMG*121*16*2*256);   // N*121*4
  _Float16* wfq  = (_Float16*)(tidx + NIMG*121*4);           // 16384 f16
  _Float16* wfkv = wfq + 16384;                              // 32768 f16
  // offpart aliases the head of kvbuf (7.9 MB of 254 MB): fully written by k_offset_part,
  // consumed by k_samp_fin, both before conv64 writes kvbuf. No footprint growth.
  float* offpart = kvbuf;                                    // 4*N*HW*2

  hipMemsetAsync(qwin, 0, (size_t)NIMG*121*128*2*4, stream);

  k_wprep<<<dim3(8), 256, 0, stream>>>(q_w, wfq, 8);
  k_wprep<<<dim3(16), 256, 0, stream>>>(kv_w, wfkv, 16);
  k_conv_mfma<32, false, true, false><<<dim3(88*22, 1, NIMG), 256, 0, stream>>>(
      x, nullptr, wfq, q_b, qbuf, qwin, nullptr);
  k_offset_part<<<dim3(11, 22, NIMG*4), 256, 0, stream>>>(
      qbuf, off_dw_w, off_dw_b, off_bn_g, off_bn_b, off_pw_w, offpart);
  k_samp_fin<<<dim3(NIMG*HW/256), 256, 0, stream>>>(offpart, samp);
  k_conv_mfma<64, true, true, true><<<dim3(88*22, 1, NIMG), 256, 0, stream>>>(
      x, samp, wfkv, kv_b, kvbuf, kwin, kvd2);
  k_routing<<<dim3(121, NIMG), 64, 0, stream>>>(qwin, kwin, tidx);
  k_attention<<<dim3(121, NIMG, 16), 256, 0, stream>>>(qbuf, kvd2, tidx, outp);
  k_sec_add<<<dim3(121, 128, NIMG), 256, 0, stream>>>(kvbuf, sec_w, sec_b, outp);
}